// Round 1
// 363.036 us; speedup vs baseline: 1.0205x; 1.0205x over previous
//
#include <hip/hip_runtime.h>
#include <math.h>

// LIF spiking-neuron scan: N=65536 rows, T=512 sequential steps/row.
// d_out = [spikes (N*T) | mems (N*T)] fp32.
//
// R3 (370us total incl. harness poison fill): single-wave blocks, LDS
// transpose staging, TILE=32, prefetch depth 1. rocprof showed the kernel
// itself <=164us (absent from top-5; fills at ~167us dominate), i.e.
// ~2-2.5 TB/s vs 6.3 TB/s achievable -> memory pipe idles between
// per-chunk bursts. Occupancy is grid-capped at 1 wave/SIMD (parallelism
// == N rows), so the only lever is CONTINUOUS ISSUE per wave.
//
// R4 design changes:
//  * TILE 32->64 (256B/row/chunk): 8 chunks instead of 16 -> half the
//    phase boundaries, 2x burst length (16 loads + 32 stores of 1KB/instr
//    back-to-back per chunk).
//  * Depth-2 register prefetch (va/vb, 128 VGPRs; fine at 1 wave/SIMD,
//    __launch_bounds__(64,1)): chunk c's loads issue ~2 chunk-times before
//    their consuming s_waitcnt -> stage never stalls on HBM latency and
//    >=16KB/wave of reads is in flight at all times.
//  * LDS cut 3->2 buffers: spikes overwrite the x tile in place (each
//    slot is read exactly once, by its own lane, before being written;
//    single-wave in-order DS pipe -> no barrier needed). 2 x 16.6KB =
//    33KB/block keeps 4 blocks/CU.
//  * Nontemporal global loads/stores: 403MB strictly-streaming traffic,
//    keep it out of L2.
//
// NUMERICS: bit-exact vs numpy verified in R1/R2 — no FMA contraction on
// the recurrence (__f*_rn intrinsics only), sigmoid(beta_) double-rounded
// once to fp32. Do not change.

typedef float f32x4 __attribute__((ext_vector_type(4)));

constexpr int N_BATCH = 65536;
constexpr int T_STEPS = 512;
constexpr int BLOCK   = 64;              // ONE wave — wave-synchronous, no barriers
constexpr int ROWS    = 64;              // rows per block (1 row/thread)
constexpr int TILE    = 64;              // steps per chunk = 256B per row
constexpr int NCH     = T_STEPS / TILE;  // 8 chunks
constexpr int PAD     = TILE + 1;        // LDS row stride: 65 == 1 mod 32 -> <=2-way banks everywhere
constexpr int RPF     = T_STEPS / 4;     // 128: global row pitch in float4

// I/O lane roles: rsub = t>>4 (0..3 rows per pass), a = t&15 (float4 within
// the 256B chunk). Each instruction covers 4 rows x 256B = 8 full 128B lines.

__device__ __forceinline__ void prefetch_chunk(f32x4 (&v)[16], const f32x4* __restrict__ xg,
                                               int base, int rsub, int a, int c) {
#pragma unroll
    for (int p = 0; p < 16; ++p)
        v[p] = __builtin_nontemporal_load(
            &xg[(size_t)(base + p * 4 + rsub) * RPF + (size_t)c * 16 + a]);
}

__device__ __forceinline__ void stage_chunk(const f32x4 (&v)[16], float* xs, int rsub, int a) {
#pragma unroll
    for (int p = 0; p < 16; ++p) {
        const int r = p * 4 + rsub;
        float* dst = &xs[r * PAD + a * 4];
        dst[0] = v[p][0]; dst[1] = v[p][1]; dst[2] = v[p][2]; dst[3] = v[p][3];
    }
}

__device__ __forceinline__ void store_chunk(const float* xs, const float* msb,
                                            f32x4* __restrict__ sg, f32x4* __restrict__ mg,
                                            int base, int rsub, int a, int c) {
#pragma unroll
    for (int p = 0; p < 16; ++p) {
        const int r = p * 4 + rsub;
        const float* srow = &xs [r * PAD + a * 4];
        const float* mrow = &msb[r * PAD + a * 4];
        const f32x4 sv = { srow[0], srow[1], srow[2], srow[3] };
        const f32x4 mv = { mrow[0], mrow[1], mrow[2], mrow[3] };
        const size_t gi = (size_t)(base + r) * RPF + (size_t)c * 16 + a;
        __builtin_nontemporal_store(sv, &sg[gi]);
        __builtin_nontemporal_store(mv, &mg[gi]);
    }
}

__global__ __launch_bounds__(BLOCK, 1) void lif_scan_kernel(
    const float* __restrict__ x,
    const float* __restrict__ beta_p,
    const float* __restrict__ thr_p,
    const float* __restrict__ init_u,
    float* __restrict__ out)
{
#pragma clang fp contract(off)
    __shared__ float xs [ROWS * PAD];   // x tile in, spike tile out (reused in place)
    __shared__ float msb[ROWS * PAD];   // mems tile

    const int t    = threadIdx.x;       // 0..63
    const int base = blockIdx.x * ROWS;
    const int rsub = t >> 4;            // 0..3: row-within-pass for I/O role
    const int a    = t & 15;            // 0..15: float4 index within 256B chunk

    const float thr  = thr_p[0];
    const float beta = (float)(1.0 / (1.0 + exp(-(double)beta_p[0])));
    float mem = __fmul_rn(init_u[base + t], thr);   // mem0, row base+t

    const f32x4* __restrict__ xg = (const f32x4*)x;
    f32x4* __restrict__ sg = (f32x4*)out;
    f32x4* __restrict__ mg = (f32x4*)(out + (size_t)N_BATCH * T_STEPS);

    f32x4 va[16], vb[16];
    prefetch_chunk(va, xg, base, rsub, a, 0);
    prefetch_chunk(vb, xg, base, rsub, a, 1);

    // compute: thread t scans row base+t over TILE steps.
    // (wave-synchronous: DS in-order + lockstep lanes; no barrier needed)
    auto compute_chunk = [&]() {
#pragma clang fp contract(off)
#pragma unroll
        for (int k = 0; k < TILE; ++k) {
            const float xv      = xs[t * PAD + k];
            const float mem_in  = mem;
            const float mem_upd = __fadd_rn(__fmul_rn(beta, mem), xv);
            const float surplus = __fsub_rn(mem_upd, thr);
            const float hard    = (surplus >= 0.0f) ? 1.0f : 0.0f;
            xs [t * PAD + k] = hard;     // spike forward value == hard (overwrites consumed x)
            msb[t * PAD + k] = mem_in;   // mems logs memory BEFORE the step
            mem = __fsub_rn(mem_upd, __fmul_rn(hard, thr));
        }
    };

    for (int c = 0; c < NCH; c += 2) {
        // ---- even chunk: data in va ----
        stage_chunk(va, xs, rsub, a);                          // waits on va loads only
        if (c + 2 < NCH) prefetch_chunk(va, xg, base, rsub, a, c + 2);  // refill immediately
        compute_chunk();
        store_chunk(xs, msb, sg, mg, base, rsub, a, c);

        // ---- odd chunk: data in vb ----
        stage_chunk(vb, xs, rsub, a);
        if (c + 3 < NCH) prefetch_chunk(vb, xg, base, rsub, a, c + 3);
        compute_chunk();
        store_chunk(xs, msb, sg, mg, base, rsub, a, c + 1);
    }
}

extern "C" void kernel_launch(void* const* d_in, const int* in_sizes, int n_in,
                              void* d_out, int out_size, void* d_ws, size_t ws_size,
                              hipStream_t stream) {
    const float* x      = (const float*)d_in[0];
    const float* beta_  = (const float*)d_in[1];
    const float* thresh = (const float*)d_in[2];
    const float* init_u = (const float*)d_in[3];
    float* out = (float*)d_out;

    dim3 block(BLOCK);
    dim3 grid(N_BATCH / ROWS);   // 1024 blocks -> 4 per CU (1 wave/SIMD)
    lif_scan_kernel<<<grid, block, 0, stream>>>(x, beta_, thresh, init_u, out);
}

// Round 3
// 361.642 us; speedup vs baseline: 1.0244x; 1.0039x over previous
//
#include <hip/hip_runtime.h>
#include <math.h>

// LIF spiking-neuron scan: N=65536 rows, T=512 sequential steps/row.
// d_out = [spikes (N*T) | mems (N*T)] fp32.
//
// History:
//  R2 direct per-lane global I/O  : ~2.5 TB/s eff (kernel ~160us)
//  R3 LDS-staged TILE=32 depth-1  : ~2.5 TB/s
//  R4 TILE=64 depth-2 NT + 2-buf  : ~2.5 TB/s (363us total incl. harness fill)
//  R5 ROWS 64->16 (4 waves/SIMD)  : FAILED mems absmax 12.86 — see below
//
// R5 bug post-mortem: the no-barrier wave-synchronous design relies on the
// HW in-order DS pipe, but the COMPILER only preserves the order of two
// shared-mem ops when it cannot prove per-thread disjointness (cross-lane
// deps are not modeled without a barrier). store's msb reads (rows
// {rsub,4+rsub,8+rsub,12+rsub}) are provably disjoint, per-thread, from the
// NEXT compute's msb writes (row t) -> LLVM sank the reads past the writes
// -> mems picked up next-chunk values (absmax ~= |dmem across a chunk|).
// xs survived because store reads / stage writes hit the SAME per-thread
// addresses -> forced order -> spikes passed. R3/R4 had the identical
// latent hazard; scheduling luck hid it.
//
// R6 fix: zero-cost COMPILER fences — asm volatile("" ::: "memory") at
// every phase boundary. Pins program order of all memory ops (HW DS pipe
// is in-order, that's all we need) without emitting any instruction and
// without the vmcnt(0) drain __syncthreads() would force on the in-flight
// prefetch. Concurrency experiment (the R5 theory) otherwise unchanged:
// ROWS=16/block, 4096 single-wave blocks -> 16 blocks/CU -> 4 waves/SIMD;
// compute on lanes 0..15, all 64 lanes cooperate on I/O; LDS 8.3KB/block.
//
// NUMERICS: bit-exact vs numpy verified in R1/R2 — no FMA contraction on
// the recurrence (__f*_rn intrinsics only), sigmoid(beta_) double-rounded
// once to fp32. Do not change.

typedef float f32x4 __attribute__((ext_vector_type(4)));

// Compiler-only memory fence: forbids reordering memory ops across this
// point. Emits NOTHING. Required at every phase boundary (see R5 bug).
#define WAVE_FENCE() asm volatile("" ::: "memory")

constexpr int N_BATCH = 65536;
constexpr int T_STEPS = 512;
constexpr int BLOCK   = 64;              // ONE wave — wave-synchronous
constexpr int ROWS    = 16;              // rows per block (compute lanes 0..15)
constexpr int TILE    = 64;              // steps per chunk = 256B per row
constexpr int NCH     = T_STEPS / TILE;  // 8 chunks
constexpr int PAD     = TILE + 1;        // LDS row stride: 65 -> <=2-way banks (free)
constexpr int RPF     = T_STEPS / 4;     // 128: global row pitch in float4
constexpr int LPC     = ROWS * TILE / (BLOCK * 4);  // 4 load instrs per chunk

// I/O lane roles: rsub = t>>4 (0..3), a = t&15 (float4 within the 256B
// chunk). Instruction p covers rows p*4+rsub -> 4 rows x 256B = 8 full
// 128B lines per instruction.

__device__ __forceinline__ void prefetch_chunk(f32x4 (&v)[LPC], const f32x4* __restrict__ xg,
                                               int base, int rsub, int a, int c) {
#pragma unroll
    for (int p = 0; p < LPC; ++p)
        v[p] = __builtin_nontemporal_load(
            &xg[(size_t)(base + p * 4 + rsub) * RPF + (size_t)c * 16 + a]);
}

__device__ __forceinline__ void stage_chunk(const f32x4 (&v)[LPC], float* xs, int rsub, int a) {
#pragma unroll
    for (int p = 0; p < LPC; ++p) {
        const int r = p * 4 + rsub;
        float* dst = &xs[r * PAD + a * 4];
        dst[0] = v[p][0]; dst[1] = v[p][1]; dst[2] = v[p][2]; dst[3] = v[p][3];
    }
}

__device__ __forceinline__ void store_chunk(const float* xs, const float* msb,
                                            f32x4* __restrict__ sg, f32x4* __restrict__ mg,
                                            int base, int rsub, int a, int c) {
#pragma unroll
    for (int p = 0; p < LPC; ++p) {
        const int r = p * 4 + rsub;
        const float* srow = &xs [r * PAD + a * 4];
        const float* mrow = &msb[r * PAD + a * 4];
        const f32x4 sv = { srow[0], srow[1], srow[2], srow[3] };
        const f32x4 mv = { mrow[0], mrow[1], mrow[2], mrow[3] };
        const size_t gi = (size_t)(base + r) * RPF + (size_t)c * 16 + a;
        __builtin_nontemporal_store(sv, &sg[gi]);
        __builtin_nontemporal_store(mv, &mg[gi]);
    }
}

__global__ __launch_bounds__(BLOCK, 1) void lif_scan_kernel(
    const float* __restrict__ x,
    const float* __restrict__ beta_p,
    const float* __restrict__ thr_p,
    const float* __restrict__ init_u,
    float* __restrict__ out)
{
#pragma clang fp contract(off)
    __shared__ float xs [ROWS * PAD];   // x tile in, spike tile out (reused in place)
    __shared__ float msb[ROWS * PAD];   // mems tile

    const int t    = threadIdx.x;       // 0..63
    const int base = blockIdx.x * ROWS;
    const int rsub = t >> 4;            // 0..3: row-within-pass for I/O role
    const int a    = t & 15;            // 0..15: float4 index within 256B chunk

    const float thr  = thr_p[0];
    const float beta = (float)(1.0 / (1.0 + exp(-(double)beta_p[0])));
    float mem = 0.0f;
    if (t < ROWS) mem = __fmul_rn(init_u[base + t], thr);   // mem0, row base+t

    const f32x4* __restrict__ xg = (const f32x4*)x;
    f32x4* __restrict__ sg = (f32x4*)out;
    f32x4* __restrict__ mg = (f32x4*)(out + (size_t)N_BATCH * T_STEPS);

    f32x4 va[LPC], vb[LPC];
    prefetch_chunk(va, xg, base, rsub, a, 0);
    prefetch_chunk(vb, xg, base, rsub, a, 1);

    // compute: lane t (<ROWS) scans row base+t over TILE steps.
    // (wave-synchronous: HW DS pipe in-order; WAVE_FENCE pins compiler order)
    auto compute_chunk = [&]() {
#pragma clang fp contract(off)
        if (t < ROWS) {
#pragma unroll
            for (int k = 0; k < TILE; ++k) {
                const float xv      = xs[t * PAD + k];
                const float mem_in  = mem;
                const float mem_upd = __fadd_rn(__fmul_rn(beta, mem), xv);
                const float surplus = __fsub_rn(mem_upd, thr);
                const float hard    = (surplus >= 0.0f) ? 1.0f : 0.0f;
                xs [t * PAD + k] = hard;     // spike forward == hard (overwrites consumed x)
                msb[t * PAD + k] = mem_in;   // mems logs memory BEFORE the step
                mem = __fsub_rn(mem_upd, __fmul_rn(hard, thr));
            }
        }
    };

    for (int c = 0; c < NCH; c += 2) {
        // ---- even chunk: data in va ----
        stage_chunk(va, xs, rsub, a);                          // waits on va loads only
        if (c + 2 < NCH) prefetch_chunk(va, xg, base, rsub, a, c + 2);
        WAVE_FENCE();   // stage xs writes  || compute xs reads
        compute_chunk();
        WAVE_FENCE();   // compute xs/msb writes || store reads
        store_chunk(xs, msb, sg, mg, base, rsub, a, c);
        WAVE_FENCE();   // store reads || next stage/compute writes

        // ---- odd chunk: data in vb ----
        stage_chunk(vb, xs, rsub, a);
        if (c + 3 < NCH) prefetch_chunk(vb, xg, base, rsub, a, c + 3);
        WAVE_FENCE();
        compute_chunk();
        WAVE_FENCE();
        store_chunk(xs, msb, sg, mg, base, rsub, a, c + 1);
        WAVE_FENCE();
    }
}

extern "C" void kernel_launch(void* const* d_in, const int* in_sizes, int n_in,
                              void* d_out, int out_size, void* d_ws, size_t ws_size,
                              hipStream_t stream) {
    const float* x      = (const float*)d_in[0];
    const float* beta_  = (const float*)d_in[1];
    const float* thresh = (const float*)d_in[2];
    const float* init_u = (const float*)d_in[3];
    float* out = (float*)d_out;

    dim3 block(BLOCK);
    dim3 grid(N_BATCH / ROWS);   // 4096 blocks -> 16 per CU (4 waves/SIMD)
    lif_scan_kernel<<<grid, block, 0, stream>>>(x, beta_, thresh, init_u, out);
}